// Round 11
// baseline (233.008 us; speedup 1.0000x reference)
//
#include <hip/hip_runtime.h>
#include <math.h>

typedef __bf16 bf16_t;
typedef __bf16 bf16x4_v __attribute__((ext_vector_type(4)));
typedef __bf16 bf16x8_t __attribute__((ext_vector_type(8)));
typedef float f32x4_t __attribute__((ext_vector_type(4)));
typedef unsigned uint2_t __attribute__((ext_vector_type(2)));
typedef unsigned uint4_t __attribute__((ext_vector_type(4)));

#define S_LEN 4096
#define DM 512
#define NH 8
#define DH 64
#define MTOT 8192  // B*S

// 1/sqrt(64) * log2(e): scores come out in log2 domain -> exp2 directly
#define Q_SCALE 0.1803368801111204f

// ws element offsets (bf16): [Xq|Xk|Xv | Wq|Wk|Wv|Wo | Qh|Kh|VTh], Ob reuses Xq
#define REG   4194304                    // 8192*512
#define WREG  262144                     // 512*512
#define W_OFF (3 * REG)                  // 12582912
#define CVT_TOTAL (3 * REG + 4 * WREG)   // 13631488
#define QH_OFF CVT_TOTAL

__device__ inline f32x4_t mfma16(bf16x8_t a, bf16x8_t b, f32x4_t c) {
    return __builtin_amdgcn_mfma_f32_16x16x32_bf16(a, b, c, 0, 0, 0);
}

// f32 pair -> packed bf16x2 via compiler casts (R4/R7-verified semantics).
__device__ inline unsigned pkbf16(float a, float b) {
    unsigned short ra = __builtin_bit_cast(unsigned short, (bf16_t)a);
    unsigned short rb = __builtin_bit_cast(unsigned short, (bf16_t)b);
    return (unsigned)ra | ((unsigned)rb << 16);
}

__device__ inline void async_copy16(const void* g, void* l) {
    __builtin_amdgcn_global_load_lds(
        (const __attribute__((address_space(1))) void*)g,
        (__attribute__((address_space(3))) void*)l, 16, 0, 0);
}

// ---------------------------------------------------------------------------
// Convert q,k,v,wq,wk,wv,wo fp32 -> bf16 into ws (one contiguous dst region).
// ---------------------------------------------------------------------------
__global__ __launch_bounds__(256) void cvt_all(
    const float* __restrict__ q, const float* __restrict__ k, const float* __restrict__ v,
    const float* __restrict__ wq, const float* __restrict__ wk,
    const float* __restrict__ wv, const float* __restrict__ wo,
    bf16_t* __restrict__ dst)
{
    long gidx = (long)blockIdx.x * 2048 + (long)threadIdx.x * 8;
    const float* src;
    long off = gidx;
    if      (gidx < 1L * REG)          { src = q; }
    else if (gidx < 2L * REG)          { src = k;  off = gidx - 1L * REG; }
    else if (gidx < 3L * REG)          { src = v;  off = gidx - 2L * REG; }
    else if (gidx < W_OFF + 1L * WREG) { src = wq; off = gidx - W_OFF; }
    else if (gidx < W_OFF + 2L * WREG) { src = wk; off = gidx - (W_OFF + 1L * WREG); }
    else if (gidx < W_OFF + 3L * WREG) { src = wv; off = gidx - (W_OFF + 2L * WREG); }
    else                               { src = wo; off = gidx - (W_OFF + 3L * WREG); }
    float4 a = *(const float4*)(src + off);
    float4 b = *(const float4*)(src + off + 4);
    bf16x8_t h;
    h[0] = (bf16_t)a.x; h[1] = (bf16_t)a.y; h[2] = (bf16_t)a.z; h[3] = (bf16_t)a.w;
    h[4] = (bf16_t)b.x; h[5] = (bf16_t)b.y; h[6] = (bf16_t)b.z; h[7] = (bf16_t)b.w;
    *(bf16x8_t*)(dst + gidx) = h;
}

// ---------------------------------------------------------------------------
// GEMM 1 (bf16): P_p = X_p @ W_p^T + b_p, p = blockIdx.z
// ---------------------------------------------------------------------------
__global__ __launch_bounds__(256) void gemm_qkv(
    const bf16_t* __restrict__ XWb,
    const float* __restrict__ B0, const float* __restrict__ B1, const float* __restrict__ B2,
    bf16_t* __restrict__ dst_base)
{
    const int p = blockIdx.z;
    const bf16_t* __restrict__ X = XWb + (size_t)p * REG;
    const bf16_t* __restrict__ W = XWb + W_OFF + (size_t)p * WREG;
    const float* __restrict__ Bi = (p == 0) ? B0 : ((p == 1) ? B1 : B2);
    bf16_t* __restrict__ dst = dst_base + (size_t)p * REG;

    const int m0 = blockIdx.x * 128;
    const int n0 = blockIdx.y * 128;
    const int tid = threadIdx.x;
    const int lane = tid & 63, wid = tid >> 6;
    const int lm = lane & 15, lg = lane >> 4;
    const int wm = (wid >> 1) * 64, wn = (wid & 1) * 64;

    __shared__ __align__(16) bf16_t smemAB[2][128 * 64];  // As | Bs, contiguous
    bf16_t* As = smemAB[0];
    bf16_t* Bs = smemAB[1];

    f32x4_t acc[4][4] = {};

    const int r0 = tid >> 3, c7 = tid & 7;
    const int cA0 = ((lg) ^ (lm & 7)) * 8;
    const int cA1 = ((4 + lg) ^ (lm & 7)) * 8;

    for (int kb = 0; kb < DM / 64; ++kb) {
        const int k0 = kb * 64;
#pragma unroll
        for (int i = 0; i < 4; ++i) {
            int row = i * 32 + r0;
            int ch = c7 ^ (row & 7);
            async_copy16(X + (size_t)(m0 + row) * DM + k0 + ch * 8, (char*)As + (i * 256 + tid) * 16);
            async_copy16(W + (size_t)(n0 + row) * DM + k0 + ch * 8, (char*)Bs + (i * 256 + tid) * 16);
        }
        __syncthreads();
#pragma unroll
        for (int kd = 0; kd < 2; ++kd) {
            const int co = kd ? cA1 : cA0;
            bf16x8_t fa[4], fb[4];
#pragma unroll
            for (int mt = 0; mt < 4; ++mt) {
                fa[mt] = *(const bf16x8_t*)(As + (wm + mt * 16 + lm) * 64 + co);
                fb[mt] = *(const bf16x8_t*)(Bs + (wn + mt * 16 + lm) * 64 + co);
            }
            if (p < 2) {
#pragma unroll
                for (int mt = 0; mt < 4; ++mt)
#pragma unroll
                    for (int nt = 0; nt < 4; ++nt)
                        acc[nt][mt] = mfma16(fb[nt], fa[mt], acc[nt][mt]);  // D[dc][s]
            } else {
#pragma unroll
                for (int mt = 0; mt < 4; ++mt)
#pragma unroll
                    for (int nt = 0; nt < 4; ++nt)
                        acc[mt][nt] = mfma16(fa[mt], fb[nt], acc[mt][nt]);  // D[s][dc]
            }
        }
        __syncthreads();
    }

    if (p == 2) {
        // V^T via LDS bounce: acc D[s][dc] -> LDS [col][s] (chunk-XOR swizzle)
        // -> 16B stores along s.
        bf16_t* tb = &smemAB[0][0];  // 128 cols x 256B = 32KB
#pragma unroll
        for (int nt = 0; nt < 4; ++nt) {
            int colL = wn + nt * 16 + lm;
            float bv = Bi[n0 + colL];
#pragma unroll
            for (int mt = 0; mt < 4; ++mt) {
                int sL = wm + mt * 16 + lg * 4;
                bf16x4_v pk;
#pragma unroll
                for (int r = 0; r < 4; ++r) pk[r] = (bf16_t)(acc[mt][nt][r] + bv);
                int byte = colL * 256 + ((((sL >> 3) ^ (colL & 15))) * 16) + (sL & 7) * 2;
                *(bf16x4_v*)((char*)tb + byte) = pk;
            }
        }
        __syncthreads();
        {
            const int colL = tid >> 1, half = tid & 1;
            const int col = n0 + colL;
            const int h = (col >> 6) & 7, dc = col & 63;
            const int bb = m0 >> 12, s0 = m0 & (S_LEN - 1);
            size_t base = (((size_t)(bb * NH + h)) * DH + dc) * S_LEN + s0;
#pragma unroll
            for (int j = 0; j < 8; ++j) {
                int chunk = half * 8 + j;
                bf16x8_t v = *(const bf16x8_t*)((char*)tb + colL * 256 + ((chunk ^ (colL & 15)) * 16));
                *(bf16x8_t*)&dst[base + chunk * 8] = v;
            }
        }
    } else {
        // head-split [B,H,S,DH]: lane holds 4 consecutive dc -> bf16x4 stores
        const float scale = (p == 0) ? Q_SCALE : 1.0f;
#pragma unroll
        for (int nt = 0; nt < 4; ++nt) {
            int ncol = n0 + wn + nt * 16 + lg * 4;
            float4 bv4 = *(const float4*)&Bi[ncol];
            int h = (ncol >> 6) & 7, dc = ncol & 63;
#pragma unroll
            for (int mt = 0; mt < 4; ++mt) {
                int m = m0 + wm + mt * 16 + lm;
                int bb = m >> 12, s = m & (S_LEN - 1);
                bf16x4_v pk;
                pk[0] = (bf16_t)((acc[nt][mt][0] + bv4.x) * scale);
                pk[1] = (bf16_t)((acc[nt][mt][1] + bv4.y) * scale);
                pk[2] = (bf16_t)((acc[nt][mt][2] + bv4.z) * scale);
                pk[3] = (bf16_t)((acc[nt][mt][3] + bv4.w) * scale);
                *(bf16x4_v*)&dst[(((size_t)(bb * NH + h)) * S_LEN + s) * DH + dc] = pk;
            }
        }
    }
}

// ---------------------------------------------------------------------------
// Flash attention v15: R2's kv-split-4 geometry (512 thr = 2qg x 4kvh, 64KB
// LDS, correctness-proven 4-way tree merge) + R7/R9's slimmed body (pq quads
// + ones-MFMA l). Why: total waves = (BHS/q_w)*kv_split; split=2 pins the
// whole kernel at 2 waves/SIMD (R9 proved LDS wasn't the cap -- the grid is).
// split=4 gives 4096 waves = 4/SIMD at 2 blocks/CU. R2 was slow ONLY from
// the launch_bounds(512,4) 64-VGPR spill; (512,2) caps >=128, demand ~84-110.
// ---------------------------------------------------------------------------
__global__ __launch_bounds__(512, 2) void flash_attn(
    const bf16_t* __restrict__ Qh, const bf16_t* __restrict__ Kh,
    const bf16_t* __restrict__ Vth, bf16_t* __restrict__ O)
{
    const int bh = blockIdx.y;  // b*8 + h
    const int q0 = blockIdx.x * 128;
    const int tid = threadIdx.x;
    const int lane = tid & 63, wid = tid >> 6;
    const int lm = lane & 15, lg = lane >> 4;
    const int qg = wid & 1;    // q-group: 64 q rows
    const int kvh = wid >> 1;  // kv quarter: 32 kv cols (0..3)

    const bf16_t* __restrict__ Qb  = Qh  + (size_t)bh * S_LEN * DH;
    const bf16_t* __restrict__ Kb  = Kh  + (size_t)bh * S_LEN * DH;
    const bf16_t* __restrict__ Vtg = Vth + (size_t)bh * S_LEN * DH;  // [d][s]

    // two staging buffers of 32KB: K(16K: 128 rows x 128B) | V(16K: 2 s-half
    // blocks of [64 d x 128B]). merge buffer (4x16KB) reuses all 64KB after.
    __shared__ __align__(16) char smem[65536];

    // Q fragments: 64 q rows x 64 dh in registers (32 VGPRs)
    bf16x8_t bQ[4][2];
#pragma unroll
    for (int nt = 0; nt < 4; ++nt)
#pragma unroll
        for (int kd = 0; kd < 2; ++kd)
            bQ[nt][kd] = *(const bf16x8_t*)(Qb + (size_t)(q0 + qg * 64 + nt * 16 + lm) * DH + kd * 32 + lg * 8);

    f32x4_t o_acc[4][4] = {};   // [d-tile][q-tile]
    f32x4_t l4[4] = {};         // ones-MFMA l accumulator (row-replicated)

    const uint4_t onesu = {0x3F803F80u, 0x3F803F80u, 0x3F803F80u, 0x3F803F80u};
    const bf16x8_t vOnes = __builtin_bit_cast(bf16x8_t, onesu);

    const int srow = tid >> 3;                 // 0..63
    const int slch = (tid & 7) ^ (srow & 7);   // source-side chunk swizzle
    const bf16_t* gK = Kb + (size_t)srow * DH + slch * 8;
    const bf16_t* gV = Vtg + (size_t)srow * S_LEN + slch * 8;

    const int cK0 = ((lg) ^ (lm & 7)) * 16;
    const int cK1 = ((4 + lg) ^ (lm & 7)) * 16;
    const int qoff = (kvh & 1) * 4;            // s-quarter chunks within V half

    // prologue: stage tile 0 into buffer 0 (4 async x 512 thr x 16B = 32KB)
    {
        char* b = smem;
#pragma unroll
        for (int j = 0; j < 2; ++j)
            async_copy16(gK + (size_t)(j * 64) * DH, b + j * 8192 + tid * 16);
#pragma unroll
        for (int i = 0; i < 2; ++i)
            async_copy16(gV + i * 64, b + 16384 + i * 8192 + tid * 16);
    }

    const int NT = S_LEN / 128;
    for (int it = 0; it < NT; ++it) {
        const char* buf = smem + (it & 1) * 32768;
        __syncthreads();  // drains this buffer's loads (vmcnt 0) + all waves

        if (it + 1 < NT) {
            char* nb = smem + ((it + 1) & 1) * 32768;
            const int kvb = (it + 1) * 128;
#pragma unroll
            for (int j = 0; j < 2; ++j)
                async_copy16(gK + (size_t)(kvb + j * 64) * DH, nb + j * 8192 + tid * 16);
#pragma unroll
            for (int i = 0; i < 2; ++i)
                async_copy16(gV + kvb + i * 64, nb + 16384 + i * 8192 + tid * 16);
        }

        const char* ksb = buf + kvh * 4096;                  // this wave's 32 K rows
        const char* vsb = buf + 16384 + (kvh >> 1) * 8192;   // s-half V block

        // --- QK + exp2 + packed-P straight into PV operand quads ---
        uint4_t pq[4];  // pq[nt] = {P(kv16 tile 0), P(kv16 tile 1)} bf16x8
#pragma unroll
        for (int mt = 0; mt < 2; ++mt) {
            const char* krow = ksb + (mt * 16 + lm) * 128;
            bf16x8_t aK0 = *(const bf16x8_t*)(krow + cK0);
            bf16x8_t aK1 = *(const bf16x8_t*)(krow + cK1);
            const int hf = mt * 2;
#pragma unroll
            for (int nt = 0; nt < 4; ++nt) {
                f32x4_t s = {};
                s = mfma16(aK0, bQ[nt][0], s);
                s = mfma16(aK1, bQ[nt][1], s);
                float e0 = __builtin_amdgcn_exp2f(s[0]);
                float e1 = __builtin_amdgcn_exp2f(s[1]);
                float e2 = __builtin_amdgcn_exp2f(s[2]);
                float e3 = __builtin_amdgcn_exp2f(s[3]);
                pq[nt][hf + 0] = pkbf16(e0, e1);
                pq[nt][hf + 1] = pkbf16(e2, e3);
            }
        }

        // --- l: col-sum of P via ones-MFMA ---
#pragma unroll
        for (int nt = 0; nt < 4; ++nt)
            l4[nt] = mfma16(vOnes, __builtin_bit_cast(bf16x8_t, pq[nt]), l4[nt]);

        // --- PV: O^T[d][q] += V^T . P^T, K=32 via pi-permuted k-slots ---
#pragma unroll
        for (int mt = 0; mt < 4; ++mt) {
            const char* vrow = vsb + (mt * 16 + lm) * 128;  // d = mt*16+lm
            int pc0 = (qoff + 0 + (lg >> 1)) ^ (lm & 7);
            int pc1 = (qoff + 2 + (lg >> 1)) ^ (lm & 7);
            uint2_t va0 = *(const uint2_t*)(vrow + pc0 * 16 + (lg & 1) * 8);
            uint2_t va1 = *(const uint2_t*)(vrow + pc1 * 16 + (lg & 1) * 8);
            bf16x8_t vA = __builtin_bit_cast(bf16x8_t, (uint4_t){va0[0], va0[1], va1[0], va1[1]});
#pragma unroll
            for (int nt = 0; nt < 4; ++nt)
                o_acc[mt][nt] = mfma16(vA, __builtin_bit_cast(bf16x8_t, pq[nt]), o_acc[mt][nt]);
        }
        // no trailing barrier: next iteration's barrier provides separation
    }

    // ---- merge across 4 kv-quarters (R2's correctness-proven tree) ----
    __syncthreads();  // all compute done before smem reuse

    float* lbuf = (float*)smem;  // 8 slots x 64 floats (consumed before o-writes)
    if (lg == 0) {
#pragma unroll
        for (int nt = 0; nt < 4; ++nt)
            lbuf[(qg * 4 + kvh) * 64 + nt * 16 + lm] = l4[nt][0];
    }
    __syncthreads();
    float inv[4];
    if (kvh == 0) {
#pragma unroll
        for (int nt = 0; nt < 4; ++nt) {
            int qi = nt * 16 + lm;
            float lt = lbuf[(qg * 4 + 0) * 64 + qi] + lbuf[(qg * 4 + 1) * 64 + qi]
                     + lbuf[(qg * 4 + 2) * 64 + qi] + lbuf[(qg * 4 + 3) * 64 + qi];
            inv[nt] = 1.0f / lt;
        }
    }
    __syncthreads();  // l consumed; o-writes may now overwrite lbuf

    // stage A: kv quarters 2,3 write partials to region qg*2 + (kvh&1)
    if (kvh >= 2) {
        char* rb = smem + (qg * 2 + (kvh & 1)) * 16384;
#pragma unroll
        for (int nt = 0; nt < 4; ++nt) {
            int qrow = nt * 16 + lm;
#pragma unroll
            for (int mt = 0; mt < 4; ++mt)
                *(f32x4_t*)(rb + qrow * 256 + (((mt * 4 + lg) ^ (qrow & 7)) * 16)) = o_acc[mt][nt];
        }
    }
    __syncthreads();
    // stage B: quarters 0,1 absorb (0<-2, 1<-3)
    if (kvh < 2) {
        const char* rb = smem + (qg * 2 + kvh) * 16384;
#pragma unroll
        for (int nt = 0; nt < 4; ++nt) {
            int qrow = nt * 16 + lm;
#pragma unroll
            for (int mt = 0; mt < 4; ++mt)
                o_acc[mt][nt] += *(const f32x4_t*)(rb + qrow * 256 + (((mt * 4 + lg) ^ (qrow & 7)) * 16));
        }
    }
    __syncthreads();
    // stage C: quarter 1 writes merged partial to region qg*2+1
    if (kvh == 1) {
        char* rb = smem + (qg * 2 + 1) * 16384;
#pragma unroll
        for (int nt = 0; nt < 4; ++nt) {
            int qrow = nt * 16 + lm;
#pragma unroll
            for (int mt = 0; mt < 4; ++mt)
                *(f32x4_t*)(rb + qrow * 256 + (((mt * 4 + lg) ^ (qrow & 7)) * 16)) = o_acc[mt][nt];
        }
    }
    __syncthreads();
    // final: quarter 0 absorbs, normalizes, stores
    if (kvh == 0) {
        const int bb = bh >> 3, h = bh & 7;
        const char* rb = smem + (qg * 2 + 1) * 16384;
#pragma unroll
        for (int nt = 0; nt < 4; ++nt) {
            int qrow = nt * 16 + lm;
            int q = q0 + qg * 64 + qrow;
            size_t base = ((size_t)(bb * S_LEN + q)) * DM + h * DH;
#pragma unroll
            for (int mt = 0; mt < 4; ++mt) {
                f32x4_t part = *(const f32x4_t*)(rb + qrow * 256 + (((mt * 4 + lg) ^ (qrow & 7)) * 16));
                bf16x4_v pkd;
#pragma unroll
                for (int r = 0; r < 4; ++r)
                    pkd[r] = (bf16_t)((o_acc[mt][nt][r] + part[r]) * inv[nt]);
                *(bf16x4_v*)&O[base + mt * 16 + lg * 4] = pkd;
            }
        }
    }
}

// ---------------------------------------------------------------------------
// GEMM 2 (bf16): out = O @ Wo^T + bo (fp32 output)
// ---------------------------------------------------------------------------
__global__ __launch_bounds__(256) void gemm_out(
    const bf16_t* __restrict__ A, const bf16_t* __restrict__ W,
    const float* __restrict__ Bi, float* __restrict__ out)
{
    const int m0 = blockIdx.x * 64;
    const int n0 = blockIdx.y * 128;
    const int tid = threadIdx.x;
    const int lane = tid & 63, wid = tid >> 6;
    const int lm = lane & 15, lg = lane >> 4;
    const int wm = (wid >> 1) * 32, wn = (wid & 1) * 64;

    __shared__ __align__(16) bf16_t As[64 * 64];
    __shared__ __align__(16) bf16_t Bs[128 * 64];

    f32x4_t acc[4][2] = {};  // [n-tile][m-tile], swapped: D[n][m]

    const int r0 = tid >> 3, c7 = tid & 7;
    const int cA0 = ((lg) ^ (lm & 7)) * 8;
    const int cA1 = ((4 + lg) ^ (lm & 7)) * 8;

    for (int kb = 0; kb < DM / 64; ++kb) {
        const int k0 = kb * 64;
#pragma unroll
        for (int i = 0; i < 2; ++i) {
            int idx = i * 256 + tid;
            int row = idx >> 3;
            int ch = (idx & 7) ^ (row & 7);
            async_copy16(A + (size_t)(m0 + row) * DM + k0 + ch * 8, (char*)As + idx * 16);
        }
#pragma unroll
        for (int i = 0; i < 4; ++i) {
            int row = i * 32 + r0;
            int ch = c7 ^ (row & 7);
            async_copy16(W + (size_t)(n0 + row) * DM + k0 + ch * 8, (char*)Bs + (i * 256 + tid) * 16);
        }
        __syncthreads();
#pragma unroll
        for (int kd = 0; kd < 2; ++kd) {
            const int co = kd ? cA1 : cA0;
            bf16x8_t fa[2], fb[4];
#pragma unroll
            for (int mt = 0; mt < 2; ++mt)
                fa[mt] = *(const bf16x8_t*)(As + (wm + mt * 16 + lm) * 64 + co);
#pragma unroll
            for (int nt = 0; nt < 4; ++nt)
                fb[nt] = *(const bf16x8_t*)(Bs + (wn + nt * 16 + lm) * 64 + co);
#pragma unroll
            for (int nt = 0; nt < 4; ++nt)
#pragma unroll
                for (int mt = 0; mt < 2; ++mt)
                    acc[nt][mt] = mfma16(fb[nt], fa[mt], acc[nt][mt]);
        }
        __syncthreads();
    }

#pragma unroll
    for (int nt = 0; nt < 4; ++nt) {
        int ncol = n0 + wn + nt * 16 + lg * 4;
        float4 bv4 = *(const float4*)&Bi[ncol];
#pragma unroll
        for (int mt = 0; mt < 2; ++mt) {
            int m = m0 + wm + mt * 16 + lm;
            float4 ov;
            ov.x = acc[nt][mt][0] + bv4.x;
            ov.y = acc[nt][mt][1] + bv4.y;
            ov.z = acc[nt][mt][2] + bv4.z;
            ov.w = acc[nt][mt][3] + bv4.w;
            *(float4*)&out[(size_t)m * DM + ncol] = ov;
        }
    }
}

// ---------------------------------------------------------------------------
extern "C" void kernel_launch(void* const* d_in, const int* in_sizes, int n_in,
                              void* d_out, int out_size, void* d_ws, size_t ws_size,
                              hipStream_t stream)
{
    const float* q  = (const float*)d_in[0];
    const float* k  = (const float*)d_in[1];
    const float* v  = (const float*)d_in[2];
    const float* wq = (const float*)d_in[3];
    const float* bq = (const float*)d_in[4];
    const float* wk = (const float*)d_in[5];
    const float* bk = (const float*)d_in[6];
    const float* wv = (const float*)d_in[7];
    const float* bv = (const float*)d_in[8];
    const float* wo = (const float*)d_in[9];
    const float* bo = (const float*)d_in[10];
    float* out = (float*)d_out;

    bf16_t* ws = (bf16_t*)d_ws;
    bf16_t* XWb = ws;                       // [Xq|Xk|Xv|Wq|Wk|Wv|Wo] bf16
    bf16_t* Qh  = ws + QH_OFF;
    bf16_t* Kh  = Qh + REG;
    bf16_t* VTh = Kh + REG;
    bf16_t* Ob  = ws;                       // reuse Xq region (dead after gemm_qkv)
    bf16_t* Wob = ws + W_OFF + 3 * (size_t)WREG;

    cvt_all<<<CVT_TOTAL / 2048, 256, 0, stream>>>(q, k, v, wq, wk, wv, wo, XWb);

    dim3 g1(MTOT / 128, DM / 128, 3);
    gemm_qkv<<<g1, 256, 0, stream>>>(XWb, bq, bk, bv, Qh);

    dim3 g2(S_LEN / 128, 2 * NH, 1);
    flash_attn<<<g2, 512, 0, stream>>>(Qh, Kh, VTh, Ob);

    dim3 g3(MTOT / 64, DM / 128, 1);
    gemm_out<<<g3, 256, 0, stream>>>(Ob, Wob, bo, out);
}

// Round 12
// 216.710 us; speedup vs baseline: 1.0752x; 1.0752x over previous
//
#include <hip/hip_runtime.h>
#include <math.h>

typedef __bf16 bf16_t;
typedef __bf16 bf16x4_v __attribute__((ext_vector_type(4)));
typedef __bf16 bf16x8_t __attribute__((ext_vector_type(8)));
typedef float f32x4_t __attribute__((ext_vector_type(4)));
typedef unsigned uint2_t __attribute__((ext_vector_type(2)));
typedef unsigned uint4_t __attribute__((ext_vector_type(4)));

#define S_LEN 4096
#define DM 512
#define NH 8
#define DH 64
#define MTOT 8192  // B*S

// 1/sqrt(64) * log2(e): scores come out in log2 domain -> exp2 directly
#define Q_SCALE 0.1803368801111204f

// ws element offsets (bf16): [Xq|Xk|Xv | Wq|Wk|Wv|Wo | Qh|Kh|VTh], Ob reuses Xq
#define REG   4194304                    // 8192*512
#define WREG  262144                     // 512*512
#define W_OFF (3 * REG)                  // 12582912
#define CVT_TOTAL (3 * REG + 4 * WREG)   // 13631488
#define QH_OFF CVT_TOTAL

__device__ inline f32x4_t mfma16(bf16x8_t a, bf16x8_t b, f32x4_t c) {
    return __builtin_amdgcn_mfma_f32_16x16x32_bf16(a, b, c, 0, 0, 0);
}

// f32 pair -> packed bf16x2 via compiler casts (R4/R7-verified semantics).
__device__ inline unsigned pkbf16(float a, float b) {
    unsigned short ra = __builtin_bit_cast(unsigned short, (bf16_t)a);
    unsigned short rb = __builtin_bit_cast(unsigned short, (bf16_t)b);
    return (unsigned)ra | ((unsigned)rb << 16);
}

__device__ inline void async_copy16(const void* g, void* l) {
    __builtin_amdgcn_global_load_lds(
        (const __attribute__((address_space(1))) void*)g,
        (__attribute__((address_space(3))) void*)l, 16, 0, 0);
}

// ---------------------------------------------------------------------------
// Convert q,k,v,wq,wk,wv,wo fp32 -> bf16 into ws (one contiguous dst region).
// ---------------------------------------------------------------------------
__global__ __launch_bounds__(256) void cvt_all(
    const float* __restrict__ q, const float* __restrict__ k, const float* __restrict__ v,
    const float* __restrict__ wq, const float* __restrict__ wk,
    const float* __restrict__ wv, const float* __restrict__ wo,
    bf16_t* __restrict__ dst)
{
    long gidx = (long)blockIdx.x * 2048 + (long)threadIdx.x * 8;
    const float* src;
    long off = gidx;
    if      (gidx < 1L * REG)          { src = q; }
    else if (gidx < 2L * REG)          { src = k;  off = gidx - 1L * REG; }
    else if (gidx < 3L * REG)          { src = v;  off = gidx - 2L * REG; }
    else if (gidx < W_OFF + 1L * WREG) { src = wq; off = gidx - W_OFF; }
    else if (gidx < W_OFF + 2L * WREG) { src = wk; off = gidx - (W_OFF + 1L * WREG); }
    else if (gidx < W_OFF + 3L * WREG) { src = wv; off = gidx - (W_OFF + 2L * WREG); }
    else                               { src = wo; off = gidx - (W_OFF + 3L * WREG); }
    float4 a = *(const float4*)(src + off);
    float4 b = *(const float4*)(src + off + 4);
    bf16x8_t h;
    h[0] = (bf16_t)a.x; h[1] = (bf16_t)a.y; h[2] = (bf16_t)a.z; h[3] = (bf16_t)a.w;
    h[4] = (bf16_t)b.x; h[5] = (bf16_t)b.y; h[6] = (bf16_t)b.z; h[7] = (bf16_t)b.w;
    *(bf16x8_t*)(dst + gidx) = h;
}

// ---------------------------------------------------------------------------
// GEMM 1 (bf16) v2: P_p = X_p @ W_p^T + b_p, p = blockIdx.z
// DOUBLE-BUFFERED staging (flash-proven pattern): prologue-stage buf0; loop:
// one barrier -> prefetch kb+1 into alt buffer -> compute current. K=512 is
// only 8 kb iterations; the old 2-barrier serial stage->drain->compute paid
// ~900cyc HBM latency per kb against only ~480cyc of MFMA. 64KB LDS.
// ---------------------------------------------------------------------------
__global__ __launch_bounds__(256) void gemm_qkv(
    const bf16_t* __restrict__ XWb,
    const float* __restrict__ B0, const float* __restrict__ B1, const float* __restrict__ B2,
    bf16_t* __restrict__ dst_base)
{
    const int p = blockIdx.z;
    const bf16_t* __restrict__ X = XWb + (size_t)p * REG;
    const bf16_t* __restrict__ W = XWb + W_OFF + (size_t)p * WREG;
    const float* __restrict__ Bi = (p == 0) ? B0 : ((p == 1) ? B1 : B2);
    bf16_t* __restrict__ dst = dst_base + (size_t)p * REG;

    const int m0 = blockIdx.x * 128;
    const int n0 = blockIdx.y * 128;
    const int tid = threadIdx.x;
    const int lane = tid & 63, wid = tid >> 6;
    const int lm = lane & 15, lg = lane >> 4;
    const int wm = (wid >> 1) * 64, wn = (wid & 1) * 64;

    // buffer b: As @ b*32768, Bs @ b*32768+16384 (16KB each)
    __shared__ __align__(16) char gsmem[65536];

    f32x4_t acc[4][4] = {};

    const int r0 = tid >> 3, c7 = tid & 7;
    const int cA0 = ((lg) ^ (lm & 7)) * 8;
    const int cA1 = ((4 + lg) ^ (lm & 7)) * 8;

    // prologue: stage kb=0 into buffer 0
#pragma unroll
    for (int i = 0; i < 4; ++i) {
        int row = i * 32 + r0;
        int ch = c7 ^ (row & 7);
        async_copy16(X + (size_t)(m0 + row) * DM + ch * 8, gsmem + (i * 256 + tid) * 16);
        async_copy16(W + (size_t)(n0 + row) * DM + ch * 8, gsmem + 16384 + (i * 256 + tid) * 16);
    }

    for (int kb = 0; kb < DM / 64; ++kb) {
        __syncthreads();  // drains buf[kb&1] loads; separates prior compute from overwrite below
        if (kb + 1 < DM / 64) {
            const int k0 = (kb + 1) * 64;
            char* nb = gsmem + ((kb + 1) & 1) * 32768;
#pragma unroll
            for (int i = 0; i < 4; ++i) {
                int row = i * 32 + r0;
                int ch = c7 ^ (row & 7);
                async_copy16(X + (size_t)(m0 + row) * DM + k0 + ch * 8, nb + (i * 256 + tid) * 16);
                async_copy16(W + (size_t)(n0 + row) * DM + k0 + ch * 8, nb + 16384 + (i * 256 + tid) * 16);
            }
        }
        const bf16_t* As = (const bf16_t*)(gsmem + (kb & 1) * 32768);
        const bf16_t* Bs = (const bf16_t*)(gsmem + (kb & 1) * 32768 + 16384);
#pragma unroll
        for (int kd = 0; kd < 2; ++kd) {
            const int co = kd ? cA1 : cA0;
            bf16x8_t fa[4], fb[4];
#pragma unroll
            for (int mt = 0; mt < 4; ++mt) {
                fa[mt] = *(const bf16x8_t*)(As + (wm + mt * 16 + lm) * 64 + co);
                fb[mt] = *(const bf16x8_t*)(Bs + (wn + mt * 16 + lm) * 64 + co);
            }
            if (p < 2) {
#pragma unroll
                for (int mt = 0; mt < 4; ++mt)
#pragma unroll
                    for (int nt = 0; nt < 4; ++nt)
                        acc[nt][mt] = mfma16(fb[nt], fa[mt], acc[nt][mt]);  // D[dc][s]
            } else {
#pragma unroll
                for (int mt = 0; mt < 4; ++mt)
#pragma unroll
                    for (int nt = 0; nt < 4; ++nt)
                        acc[mt][nt] = mfma16(fa[mt], fb[nt], acc[mt][nt]);  // D[s][dc]
            }
        }
        // no trailing barrier: next iteration's barrier provides separation
    }

    if (p == 2) {
        // V^T via LDS bounce: acc D[s][dc] -> LDS [col][s] (chunk-XOR swizzle)
        // -> 16B stores along s.
        __syncthreads();  // all waves done reading the last staging buffer
        bf16_t* tb = (bf16_t*)gsmem;  // 128 cols x 256B = 32KB
#pragma unroll
        for (int nt = 0; nt < 4; ++nt) {
            int colL = wn + nt * 16 + lm;
            float bv = Bi[n0 + colL];
#pragma unroll
            for (int mt = 0; mt < 4; ++mt) {
                int sL = wm + mt * 16 + lg * 4;
                bf16x4_v pk;
#pragma unroll
                for (int r = 0; r < 4; ++r) pk[r] = (bf16_t)(acc[mt][nt][r] + bv);
                int byte = colL * 256 + ((((sL >> 3) ^ (colL & 15))) * 16) + (sL & 7) * 2;
                *(bf16x4_v*)((char*)tb + byte) = pk;
            }
        }
        __syncthreads();
        {
            const int colL = tid >> 1, half = tid & 1;
            const int col = n0 + colL;
            const int h = (col >> 6) & 7, dc = col & 63;
            const int bb = m0 >> 12, s0 = m0 & (S_LEN - 1);
            size_t base = (((size_t)(bb * NH + h)) * DH + dc) * S_LEN + s0;
#pragma unroll
            for (int j = 0; j < 8; ++j) {
                int chunk = half * 8 + j;
                bf16x8_t v = *(const bf16x8_t*)((char*)tb + colL * 256 + ((chunk ^ (colL & 15)) * 16));
                *(bf16x8_t*)&dst[base + chunk * 8] = v;
            }
        }
    } else {
        // head-split [B,H,S,DH]: lane holds 4 consecutive dc -> bf16x4 stores
        const float scale = (p == 0) ? Q_SCALE : 1.0f;
#pragma unroll
        for (int nt = 0; nt < 4; ++nt) {
            int ncol = n0 + wn + nt * 16 + lg * 4;
            float4 bv4 = *(const float4*)&Bi[ncol];
            int h = (ncol >> 6) & 7, dc = ncol & 63;
#pragma unroll
            for (int mt = 0; mt < 4; ++mt) {
                int m = m0 + wm + mt * 16 + lm;
                int bb = m >> 12, s = m & (S_LEN - 1);
                bf16x4_v pk;
                pk[0] = (bf16_t)((acc[nt][mt][0] + bv4.x) * scale);
                pk[1] = (bf16_t)((acc[nt][mt][1] + bv4.y) * scale);
                pk[2] = (bf16_t)((acc[nt][mt][2] + bv4.z) * scale);
                pk[3] = (bf16_t)((acc[nt][mt][3] + bv4.w) * scale);
                *(bf16x4_v*)&dst[(((size_t)(bb * NH + h)) * S_LEN + s) * DH + dc] = pk;
            }
        }
    }
}

// ---------------------------------------------------------------------------
// Flash attention v12 (R7 verbatim, best measured 87.3us): R1 structure +
// pq quads + ones-MFMA l. R11 falsified the wave-starvation theory (kv_split4
// regressed); this 2-wave/SIMD 2-block config is the local optimum.
// ---------------------------------------------------------------------------
__global__ __launch_bounds__(256, 2) void flash_attn(
    const bf16_t* __restrict__ Qh, const bf16_t* __restrict__ Kh,
    const bf16_t* __restrict__ Vth, bf16_t* __restrict__ O)
{
    const int bh = blockIdx.y;  // b*8 + h
    const int q0 = blockIdx.x * 128;
    const int tid = threadIdx.x;
    const int lane = tid & 63, wid = tid >> 6;
    const int lm = lane & 15, lg = lane >> 4;
    const int qg = wid & 1;    // q-group: 64 q rows
    const int kvh = wid >> 1;  // kv half: 64 kv cols

    const bf16_t* __restrict__ Qb  = Qh  + (size_t)bh * S_LEN * DH;
    const bf16_t* __restrict__ Kb  = Kh  + (size_t)bh * S_LEN * DH;
    const bf16_t* __restrict__ Vtg = Vth + (size_t)bh * S_LEN * DH;  // [d][s]

    // two staging buffers of 32KB: K(16K: 128 rows x 128B) | V0(8K) V1(8K).
    // merge buffer (35328B) reuses buffer space after the loop.
    __shared__ __align__(16) char smem[65536];

    // Q fragments: 64 q rows x 64 dh in registers (32 VGPRs)
    bf16x8_t bQ[4][2];
#pragma unroll
    for (int nt = 0; nt < 4; ++nt)
#pragma unroll
        for (int kd = 0; kd < 2; ++kd)
            bQ[nt][kd] = *(const bf16x8_t*)(Qb + (size_t)(q0 + qg * 64 + nt * 16 + lm) * DH + kd * 32 + lg * 8);

    f32x4_t o_acc[4][4] = {};   // [d-tile][q-tile]
    f32x4_t l4[4] = {};         // ones-MFMA l accumulator (row-replicated)

    const uint4_t onesu = {0x3F803F80u, 0x3F803F80u, 0x3F803F80u, 0x3F803F80u};
    const bf16x8_t vOnes = __builtin_bit_cast(bf16x8_t, onesu);

    const int srow = tid >> 3;                 // 0..31
    const int slch = (tid & 7) ^ (srow & 7);   // source-side chunk swizzle
    const bf16_t* gK = Kb + (size_t)srow * DH + slch * 8;
    const bf16_t* gV = Vtg + (size_t)srow * S_LEN + slch * 8;

    const int cK0 = ((lg) ^ (lm & 7)) * 16;
    const int cK1 = ((4 + lg) ^ (lm & 7)) * 16;

    // prologue: stage tile 0 into buffer 0 (8 async x 256 thr x 16B = 32KB)
    {
        char* b = smem;
#pragma unroll
        for (int i = 0; i < 4; ++i)
            async_copy16(gK + (size_t)(32 * i) * DH, b + i * 4096 + tid * 16);
#pragma unroll
        for (int i = 0; i < 4; ++i)
            async_copy16(gV + (size_t)(i & 1) * 32 * S_LEN + (i >> 1) * 64,
                         b + 16384 + i * 4096 + tid * 16);
    }

    const int NT = S_LEN / 128;
    for (int it = 0; it < NT; ++it) {
        const char* buf = smem + (it & 1) * 32768;
        __syncthreads();  // drains this buffer's loads (vmcnt 0) + all waves

        if (it + 1 < NT) {
            char* nb = smem + ((it + 1) & 1) * 32768;
            const int kvb = (it + 1) * 128;
#pragma unroll
            for (int i = 0; i < 4; ++i)
                async_copy16(gK + (size_t)(kvb + 32 * i) * DH, nb + i * 4096 + tid * 16);
#pragma unroll
            for (int i = 0; i < 4; ++i)
                async_copy16(gV + (size_t)(i & 1) * 32 * S_LEN + kvb + (i >> 1) * 64,
                             nb + 16384 + i * 4096 + tid * 16);
        }

        const char* ksb = buf + kvh * 8192;
        const char* vsb = buf + 16384 + kvh * 8192;

        // --- QK + exp2 + packed-P, written straight into PV operand quads ---
        // pq[cc][nt] = {P(kv16 tile 2cc), P(kv16 tile 2cc+1)} packed bf16x8
        uint4_t pq[2][4];
#pragma unroll
        for (int mt = 0; mt < 4; ++mt) {
            const char* krow = ksb + (mt * 16 + lm) * 128;
            bf16x8_t aK0 = *(const bf16x8_t*)(krow + cK0);
            bf16x8_t aK1 = *(const bf16x8_t*)(krow + cK1);
            const int cc = mt >> 1, hf = (mt & 1) * 2;
#pragma unroll
            for (int nt = 0; nt < 4; ++nt) {
                f32x4_t s = {};
                s = mfma16(aK0, bQ[nt][0], s);
                s = mfma16(aK1, bQ[nt][1], s);
                float e0 = __builtin_amdgcn_exp2f(s[0]);
                float e1 = __builtin_amdgcn_exp2f(s[1]);
                float e2 = __builtin_amdgcn_exp2f(s[2]);
                float e3 = __builtin_amdgcn_exp2f(s[3]);
                pq[cc][nt][hf + 0] = pkbf16(e0, e1);
                pq[cc][nt][hf + 1] = pkbf16(e2, e3);
            }
        }

        // --- l: col-sum of P via ones-MFMA (replaces 48 adds + shfl) ---
#pragma unroll
        for (int cc = 0; cc < 2; ++cc)
#pragma unroll
            for (int nt = 0; nt < 4; ++nt)
                l4[nt] = mfma16(vOnes, __builtin_bit_cast(bf16x8_t, pq[cc][nt]), l4[nt]);

        // --- PV: O^T[d][q] += V^T . P^T, K=32 via pi-permuted k-slots ---
#pragma unroll
        for (int mt = 0; mt < 4; ++mt) {
            const char* vrow = vsb + (mt * 16 + lm) * 128;  // d = mt*16+lm
#pragma unroll
            for (int cc = 0; cc < 2; ++cc) {
                const int ca = 2 * cc, cb = 2 * cc + 1;
                int pc0 = (ca * 2 + (lg >> 1)) ^ (lm & 7);
                int pc1 = (cb * 2 + (lg >> 1)) ^ (lm & 7);
                uint2_t va0 = *(const uint2_t*)(vrow + pc0 * 16 + (lg & 1) * 8);
                uint2_t va1 = *(const uint2_t*)(vrow + pc1 * 16 + (lg & 1) * 8);
                bf16x8_t vA = __builtin_bit_cast(bf16x8_t, (uint4_t){va0[0], va0[1], va1[0], va1[1]});
#pragma unroll
                for (int nt = 0; nt < 4; ++nt)
                    o_acc[mt][nt] = mfma16(vA, __builtin_bit_cast(bf16x8_t, pq[cc][nt]), o_acc[mt][nt]);
            }
        }
        // no trailing barrier: next iteration's barrier provides separation
    }

    __syncthreads();  // all compute done before smem is reused for the merge

    // merge across the 2 kv-halves: stride 68 floats keeps b128 16B-aligned.
    float* ob = (float*)smem + qg * (64 * 68);
    float* lb = (float*)(smem + 34816);

    if (kvh == 1) {
#pragma unroll
        for (int nt = 0; nt < 4; ++nt) {
#pragma unroll
            for (int mt = 0; mt < 4; ++mt)
                *(f32x4_t*)&ob[(nt * 16 + lm) * 68 + mt * 16 + lg * 4] = o_acc[mt][nt];
            if (lg == 0) lb[qg * 64 + nt * 16 + lm] = l4[nt][0];
        }
    }
    __syncthreads();
    if (kvh == 0) {
        const int bb = bh >> 3, h = bh & 7;
#pragma unroll
        for (int nt = 0; nt < 4; ++nt) {
            float ltot = l4[nt][0] + lb[qg * 64 + nt * 16 + lm];
            float inv = 1.0f / ltot;
            int q = q0 + qg * 64 + nt * 16 + lm;
            size_t base = ((size_t)(bb * S_LEN + q)) * DM + h * DH;
#pragma unroll
            for (int mt = 0; mt < 4; ++mt) {
                f32x4_t orow = *(const f32x4_t*)&ob[(nt * 16 + lm) * 68 + mt * 16 + lg * 4];
                bf16x4_v pkd;
#pragma unroll
                for (int r = 0; r < 4; ++r)
                    pkd[r] = (bf16_t)((o_acc[mt][nt][r] + orow[r]) * inv);
                *(bf16x4_v*)&O[base + mt * 16 + lg * 4] = pkd;
            }
        }
    }
}

// ---------------------------------------------------------------------------
// GEMM 2 (bf16) v2: out = O @ Wo^T + bo (fp32 output), double-buffered
// staging (same pattern as gemm_qkv v2). Buffer b: As @ b*24576 (8KB),
// Bs @ b*24576+8192 (16KB); 48KB total.
// ---------------------------------------------------------------------------
__global__ __launch_bounds__(256) void gemm_out(
    const bf16_t* __restrict__ A, const bf16_t* __restrict__ W,
    const float* __restrict__ Bi, float* __restrict__ out)
{
    const int m0 = blockIdx.x * 64;
    const int n0 = blockIdx.y * 128;
    const int tid = threadIdx.x;
    const int lane = tid & 63, wid = tid >> 6;
    const int lm = lane & 15, lg = lane >> 4;
    const int wm = (wid >> 1) * 32, wn = (wid & 1) * 64;

    __shared__ __align__(16) char gsmem[49152];

    f32x4_t acc[4][2] = {};  // [n-tile][m-tile], swapped: D[n][m]

    const int r0 = tid >> 3, c7 = tid & 7;
    const int cA0 = ((lg) ^ (lm & 7)) * 8;
    const int cA1 = ((4 + lg) ^ (lm & 7)) * 8;

    // prologue: stage kb=0 into buffer 0
#pragma unroll
    for (int i = 0; i < 2; ++i) {
        int idx = i * 256 + tid;
        int row = idx >> 3;
        int ch = (idx & 7) ^ (row & 7);
        async_copy16(A + (size_t)(m0 + row) * DM + ch * 8, gsmem + idx * 16);
    }
#pragma unroll
    for (int i = 0; i < 4; ++i) {
        int row = i * 32 + r0;
        int ch = c7 ^ (row & 7);
        async_copy16(W + (size_t)(n0 + row) * DM + ch * 8, gsmem + 8192 + (i * 256 + tid) * 16);
    }

    for (int kb = 0; kb < DM / 64; ++kb) {
        __syncthreads();
        if (kb + 1 < DM / 64) {
            const int k0 = (kb + 1) * 64;
            char* nb = gsmem + ((kb + 1) & 1) * 24576;
#pragma unroll
            for (int i = 0; i < 2; ++i) {
                int idx = i * 256 + tid;
                int row = idx >> 3;
                int ch = (idx & 7) ^ (row & 7);
                async_copy16(A + (size_t)(m0 + row) * DM + k0 + ch * 8, nb + idx * 16);
            }
#pragma unroll
            for (int i = 0; i < 4; ++i) {
                int row = i * 32 + r0;
                int ch = c7 ^ (row & 7);
                async_copy16(W + (size_t)(n0 + row) * DM + k0 + ch * 8, nb + 8192 + (i * 256 + tid) * 16);
            }
        }
        const bf16_t* As = (const bf16_t*)(gsmem + (kb & 1) * 24576);
        const bf16_t* Bs = (const bf16_t*)(gsmem + (kb & 1) * 24576 + 8192);
#pragma unroll
        for (int kd = 0; kd < 2; ++kd) {
            const int co = kd ? cA1 : cA0;
            bf16x8_t fa[2], fb[4];
#pragma unroll
            for (int mt = 0; mt < 2; ++mt)
                fa[mt] = *(const bf16x8_t*)(As + (wm + mt * 16 + lm) * 64 + co);
#pragma unroll
            for (int nt = 0; nt < 4; ++nt)
                fb[nt] = *(const bf16x8_t*)(Bs + (wn + nt * 16 + lm) * 64 + co);
#pragma unroll
            for (int nt = 0; nt < 4; ++nt)
#pragma unroll
                for (int mt = 0; mt < 2; ++mt)
                    acc[nt][mt] = mfma16(fb[nt], fa[mt], acc[nt][mt]);
        }
        // no trailing barrier: next iteration's barrier provides separation
    }

#pragma unroll
    for (int nt = 0; nt < 4; ++nt) {
        int ncol = n0 + wn + nt * 16 + lg * 4;
        float4 bv4 = *(const float4*)&Bi[ncol];
#pragma unroll
        for (int mt = 0; mt < 2; ++mt) {
            int m = m0 + wm + mt * 16 + lm;
            float4 ov;
            ov.x = acc[nt][mt][0] + bv4.x;
            ov.y = acc[nt][mt][1] + bv4.y;
            ov.z = acc[nt][mt][2] + bv4.z;
            ov.w = acc[nt][mt][3] + bv4.w;
            *(float4*)&out[(size_t)m * DM + ncol] = ov;
        }
    }
}

// ---------------------------------------------------------------------------
extern "C" void kernel_launch(void* const* d_in, const int* in_sizes, int n_in,
                              void* d_out, int out_size, void* d_ws, size_t ws_size,
                              hipStream_t stream)
{
    const float* q  = (const float*)d_in[0];
    const float* k  = (const float*)d_in[1];
    const float* v  = (const float*)d_in[2];
    const float* wq = (const float*)d_in[3];
    const float* bq = (const float*)d_in[4];
    const float* wk = (const float*)d_in[5];
    const float* bk = (const float*)d_in[6];
    const float* wv = (const float*)d_in[7];
    const float* bv = (const float*)d_in[8];
    const float* wo = (const float*)d_in[9];
    const float* bo = (const float*)d_in[10];
    float* out = (float*)d_out;

    bf16_t* ws = (bf16_t*)d_ws;
    bf16_t* XWb = ws;                       // [Xq|Xk|Xv|Wq|Wk|Wv|Wo] bf16
    bf16_t* Qh  = ws + QH_OFF;
    bf16_t* Kh  = Qh + REG;
    bf16_t* VTh = Kh + REG;
    bf16_t* Ob  = ws;                       // reuse Xq region (dead after gemm_qkv)
    bf16_t* Wob = ws + W_OFF + 3 * (size_t)WREG;

    cvt_all<<<CVT_TOTAL / 2048, 256, 0, stream>>>(q, k, v, wq, wk, wv, wo, XWb);

    dim3 g1(MTOT / 128, DM / 128, 3);
    gemm_qkv<<<g1, 256, 0, stream>>>(XWb, bq, bk, bv, Qh);

    dim3 g2(S_LEN / 128, 2 * NH, 1);
    flash_attn<<<g2, 256, 0, stream>>>(Qh, Kh, VTh, Ob);

    dim3 g3(MTOT / 64, DM / 128, 1);
    gemm_out<<<g3, 256, 0, stream>>>(Ob, Wob, bo, out);
}